// Round 1
// baseline (2052.976 us; speedup 1.0000x reference)
//
#include <hip/hip_runtime.h>

// APPNP: h0 = relu(x@W1+b1)@W2+b2 ; 10x: h = 0.9*(D^-1/2 A_sl D^-1/2 h) + 0.1*h0
// Strategy: bf16-MFMA fused MLP; CSR-by-dst build once; gather-only propagation.
// norm factorization: agg[d] = dinv[d]*( sum_{e:dst=d} dinv[src]*h[src] ) + dinv[d]^2*h[d]

typedef unsigned short u16;
typedef unsigned int   u32;
typedef __bf16 bfx8 __attribute__((ext_vector_type(8)));
typedef float  f32x4 __attribute__((ext_vector_type(4)));

__device__ __forceinline__ u16 f2bf(float f) {
    u32 u = __float_as_uint(f);
    u += 0x7fffu + ((u >> 16) & 1u);   // RNE
    return (u16)(u >> 16);
}

// ---------------- graph build ----------------

__global__ void hist_kernel(const int* __restrict__ dst, int* __restrict__ indeg, int E) {
    int i = blockIdx.x * 256 + threadIdx.x;
    if (i < E) atomicAdd(&indeg[dst[i]], 1);
}

// block-level exclusive scan (1024/block), emits per-block totals
__global__ __launch_bounds__(1024) void scan1_kernel(const int* __restrict__ indeg,
                                                     int* __restrict__ rp,
                                                     int* __restrict__ bsum, int N) {
    __shared__ int tmp[1024];
    int tid = threadIdx.x;
    int i = blockIdx.x * 1024 + tid;
    int v = (i < N) ? indeg[i] : 0;
    tmp[tid] = v;
    __syncthreads();
    for (int off = 1; off < 1024; off <<= 1) {
        int t = 0;
        if (tid >= off) t = tmp[tid - off];
        __syncthreads();
        if (tid >= off) tmp[tid] += t;
        __syncthreads();
    }
    if (i < N) rp[i] = tmp[tid] - v;          // exclusive within block
    if (tid == 1023) bsum[blockIdx.x] = tmp[1023];
}

__global__ void scan2_kernel(const int* __restrict__ bsum, int* __restrict__ boff, int nb) {
    __shared__ int s[128];
    int tid = threadIdx.x;
    s[tid] = (tid < nb) ? bsum[tid] : 0;
    __syncthreads();
    if (tid == 0) {
        int run = 0;
        for (int j = 0; j < nb; ++j) { int t = s[j]; s[j] = run; run += t; }
    }
    __syncthreads();
    if (tid < nb) boff[tid] = s[tid];
}

__global__ void scan3_kernel(int* __restrict__ rp, const int* __restrict__ boff,
                             int* __restrict__ cursor, const int* __restrict__ indeg,
                             float* __restrict__ dinv, int N, int E) {
    int i = blockIdx.x * 256 + threadIdx.x;
    if (i < N) {
        int v = rp[i] + boff[i >> 10];
        rp[i] = v;
        cursor[i] = v;
        dinv[i] = rsqrtf(1.0f + (float)indeg[i]);   // +1 self-loop
    } else if (i == N) {
        rp[N] = E;
    }
}

__global__ void scatter_kernel(const int* __restrict__ src, const int* __restrict__ dst,
                               int* __restrict__ cursor, int* __restrict__ csr, int E) {
    int i = blockIdx.x * 256 + threadIdx.x;
    if (i < E) {
        int d = dst[i];
        int pos = atomicAdd(&cursor[d], 1);
        csr[pos] = src[i];
    }
}

// ---------------- weight pre-transpose to bf16 ----------------

__global__ void prepw1_kernel(const float* __restrict__ W1, u16* __restrict__ W1t) {
    int id = blockIdx.x * 256 + threadIdx.x;   // id = k*256 + n, k<512, n<256
    int k = id >> 8, n = id & 255;
    W1t[n * 512 + k] = f2bf(W1[id]);
}

__global__ void prepw2_kernel(const float* __restrict__ W2, u16* __restrict__ W2t) {
    int id = blockIdx.x * 256 + threadIdx.x;   // id = k*64 + n, k<256, n<64
    int k = id >> 6, n = id & 63;
    W2t[n * 256 + k] = f2bf(W2[id]);
}

// ---------------- fused MLP: out = relu(x@W1+b1)@W2+b2 -> h0 and hA ----------------
// block: 64 rows of x, 256 threads (4 waves). GEMM1: wave w covers hidden cols [64w,64w+64).
// mfma_f32_16x16x32_bf16: A[m=lane&15][k=(lane>>4)*8+j]; B[n=lane&15][k=same]; D col=lane&15,row=(lane>>4)*4+r

__global__ __launch_bounds__(256) void mlp_kernel(
        const float* __restrict__ x, const u16* __restrict__ W1t,
        const float* __restrict__ b1, const u16* __restrict__ W2t,
        const float* __restrict__ b2, float* __restrict__ h0,
        float* __restrict__ hA, int N) {
    __shared__ char lds[65536];
    u16* xs  = (u16*)lds;              // phase1: [64][40] (pad 8 for banks), 5120 B
    u16* w1s = (u16*)(lds + 5120);     // phase1: [256][40], 20480 B
    u16* h1s = (u16*)lds;              // phase2: [64][256], 32768 B
    u16* w2s = (u16*)(lds + 32768);    // phase2: [64][256], 32768 B

    const int tid  = threadIdx.x;
    const int wave = tid >> 6;
    const int lane = tid & 63;
    const int lq   = lane >> 4;        // quad
    const int lr   = lane & 15;
    const int blockRow = blockIdx.x * 64;

    f32x4 acc[4][4];                   // [mt][nt]
#pragma unroll
    for (int a = 0; a < 4; ++a)
#pragma unroll
        for (int b = 0; b < 4; ++b) acc[a][b] = (f32x4){0.f, 0.f, 0.f, 0.f};

    // ---- GEMM1: K=512 in steps of 32 ----
    for (int kk = 0; kk < 512; kk += 32) {
        __syncthreads();
        // stage x tile 64x32 (fp32 -> bf16)
        {
            int r = tid >> 2, c = (tid & 3) << 3;       // 8 floats each
            int gr = blockRow + r;
            float v[8];
            if (gr < N) {
                const float* p = x + (size_t)gr * 512 + kk + c;
                float4 u0 = *(const float4*)p;
                float4 u1 = *(const float4*)(p + 4);
                v[0]=u0.x; v[1]=u0.y; v[2]=u0.z; v[3]=u0.w;
                v[4]=u1.x; v[5]=u1.y; v[6]=u1.z; v[7]=u1.w;
            } else {
#pragma unroll
                for (int j = 0; j < 8; ++j) v[j] = 0.f;
            }
            u32 pk[4];
#pragma unroll
            for (int j = 0; j < 4; ++j)
                pk[j] = (u32)f2bf(v[2*j]) | ((u32)f2bf(v[2*j+1]) << 16);
            uint4 st = make_uint4(pk[0], pk[1], pk[2], pk[3]);
            *(uint4*)&xs[r * 40 + c] = st;
        }
        // stage W1t tile 256x32 (already bf16, [n][k] layout)
        {
            const uint4* p = (const uint4*)(W1t + (size_t)tid * 512 + kk);
            uint4* q = (uint4*)&w1s[tid * 40];
            q[0] = p[0]; q[1] = p[1]; q[2] = p[2]; q[3] = p[3];
        }
        __syncthreads();
        bfx8 fa[4], fb[4];
#pragma unroll
        for (int mt = 0; mt < 4; ++mt)
            fa[mt] = *(bfx8*)&xs[(mt * 16 + lr) * 40 + lq * 8];
#pragma unroll
        for (int nt = 0; nt < 4; ++nt)
            fb[nt] = *(bfx8*)&w1s[(wave * 64 + nt * 16 + lr) * 40 + lq * 8];
#pragma unroll
        for (int mt = 0; mt < 4; ++mt)
#pragma unroll
            for (int nt = 0; nt < 4; ++nt)
                acc[mt][nt] = __builtin_amdgcn_mfma_f32_16x16x32_bf16(
                    fa[mt], fb[nt], acc[mt][nt], 0, 0, 0);
    }
    __syncthreads();   // done reading xs/w1s; reuse as h1s

    // ---- epilogue1: bias+relu -> h1s (bf16) ----
#pragma unroll
    for (int nt = 0; nt < 4; ++nt) {
        int col = wave * 64 + nt * 16 + lr;
        float bb = b1[col];
#pragma unroll
        for (int mt = 0; mt < 4; ++mt)
#pragma unroll
            for (int r = 0; r < 4; ++r) {
                int row = mt * 16 + lq * 4 + r;
                float v = acc[mt][nt][r] + bb;
                v = v > 0.f ? v : 0.f;
                h1s[row * 256 + col] = f2bf(v);
            }
    }
    // stage W2t [64][256] bf16
    {
        int nn = tid >> 2, seg = (tid & 3) * 64;
        const uint4* p = (const uint4*)(W2t + nn * 256 + seg);
        uint4* q = (uint4*)&w2s[nn * 256 + seg];
#pragma unroll
        for (int j = 0; j < 8; ++j) q[j] = p[j];
    }
    __syncthreads();

    // ---- GEMM2: wave w -> rows [16w,16w+16), cols 0..63, K=256 ----
    f32x4 acc2[4];
#pragma unroll
    for (int a = 0; a < 4; ++a) acc2[a] = (f32x4){0.f, 0.f, 0.f, 0.f};
    for (int kk = 0; kk < 256; kk += 32) {
        bfx8 a = *(bfx8*)&h1s[(wave * 16 + lr) * 256 + kk + lq * 8];
#pragma unroll
        for (int nt = 0; nt < 4; ++nt) {
            bfx8 b = *(bfx8*)&w2s[(nt * 16 + lr) * 256 + kk + lq * 8];
            acc2[nt] = __builtin_amdgcn_mfma_f32_16x16x32_bf16(a, b, acc2[nt], 0, 0, 0);
        }
    }
    // ---- epilogue2: bias, store to h0 and hA ----
#pragma unroll
    for (int nt = 0; nt < 4; ++nt) {
        int col = nt * 16 + lr;
        float bb = b2[col];
#pragma unroll
        for (int r = 0; r < 4; ++r) {
            int row = wave * 16 + lq * 4 + r;
            int gr = blockRow + row;
            if (gr < N) {
                float v = acc2[nt][r] + bb;
                size_t idx = (size_t)gr * 64 + col;
                h0[idx] = v;
                hA[idx] = v;
            }
        }
    }
}

// ---------------- propagation: gather-only, 16 threads/node, float4/lane ----------------

__global__ __launch_bounds__(256) void prop_kernel(
        const float* __restrict__ hin, const float* __restrict__ h0,
        const float* __restrict__ dinv, const int* __restrict__ rp,
        const int* __restrict__ csr, float* __restrict__ hout, int N) {
    int t = blockIdx.x * 256 + threadIdx.x;
    int i = t >> 4;
    int l = t & 15;
    if (i >= N) return;
    int beg = rp[i], end = rp[i + 1];
    float ax = 0.f, ay = 0.f, az = 0.f, aw = 0.f;
    for (int e = beg; e < end; ++e) {
        int s = csr[e];
        float w = dinv[s];
        float4 g = *(const float4*)(hin + (size_t)s * 64 + l * 4);
        ax = fmaf(w, g.x, ax);
        ay = fmaf(w, g.y, ay);
        az = fmaf(w, g.z, az);
        aw = fmaf(w, g.w, aw);
    }
    float di = dinv[i];
    float c1 = 0.9f * di;
    float c2 = 0.9f * di * di;
    float4 hi  = *(const float4*)(hin + (size_t)i * 64 + l * 4);
    float4 h0v = *(const float4*)(h0  + (size_t)i * 64 + l * 4);
    float4 o;
    o.x = fmaf(c1, ax, fmaf(c2, hi.x, 0.1f * h0v.x));
    o.y = fmaf(c1, ay, fmaf(c2, hi.y, 0.1f * h0v.y));
    o.z = fmaf(c1, az, fmaf(c2, hi.z, 0.1f * h0v.z));
    o.w = fmaf(c1, aw, fmaf(c2, hi.w, 0.1f * h0v.w));
    *(float4*)(hout + (size_t)i * 64 + l * 4) = o;
}

// ---------------- launch ----------------

extern "C" void kernel_launch(void* const* d_in, const int* in_sizes, int n_in,
                              void* d_out, int out_size, void* d_ws, size_t ws_size,
                              hipStream_t stream) {
    const float* x  = (const float*)d_in[0];
    const int*   ei = (const int*)d_in[1];
    const float* W1 = (const float*)d_in[2];
    const float* b1 = (const float*)d_in[3];
    const float* W2 = (const float*)d_in[4];
    const float* b2 = (const float*)d_in[5];
    const int N = in_sizes[0] / 512;
    const int E = in_sizes[1] / 2;
    const int* src = ei;
    const int* dst = ei + E;

    char* w = (char*)d_ws;
    size_t off = 0;
    auto alloc = [&](size_t bytes) -> char* {
        char* p = w + off;
        off = (off + bytes + 1023) & ~(size_t)1023;
        return p;
    };
    int*   indeg  = (int*)alloc((size_t)N * 4);
    int*   rp     = (int*)alloc(((size_t)N + 1) * 4);
    int*   cursor = (int*)alloc((size_t)N * 4);
    int*   bsum   = (int*)alloc(512);
    int*   boff   = (int*)alloc(512);
    float* dinv   = (float*)alloc((size_t)N * 4);
    int*   csr    = (int*)alloc((size_t)E * 4);
    u16*   W1t    = (u16*)alloc(512 * 256 * 2);
    u16*   W2t    = (u16*)alloc(256 * 64 * 2);
    float* h0     = (float*)alloc((size_t)N * 64 * 4);
    float* hA     = (float*)alloc((size_t)N * 64 * 4);
    float* hB     = (float*)alloc((size_t)N * 64 * 4);
    // total ws use: ~92 MB

    hipMemsetAsync(indeg, 0, (size_t)N * 4, stream);
    hist_kernel<<<(E + 255) / 256, 256, 0, stream>>>(dst, indeg, E);
    int nb = (N + 1023) / 1024;
    scan1_kernel<<<nb, 1024, 0, stream>>>(indeg, rp, bsum, N);
    scan2_kernel<<<1, 128, 0, stream>>>(bsum, boff, nb);
    scan3_kernel<<<(N + 256) / 256, 256, 0, stream>>>(rp, boff, cursor, indeg, dinv, N, E);
    scatter_kernel<<<(E + 255) / 256, 256, 0, stream>>>(src, dst, cursor, csr, E);
    prepw1_kernel<<<512, 256, 0, stream>>>(W1, W1t);
    prepw2_kernel<<<64, 256, 0, stream>>>(W2, W2t);
    mlp_kernel<<<(N + 63) / 64, 256, 0, stream>>>(x, W1t, b1, W2t, b2, h0, hA, N);

    const float* pin = hA;
    for (int it = 0; it < 10; ++it) {
        float* pout = (it == 9) ? (float*)d_out : ((it & 1) ? hA : hB);
        prop_kernel<<<(N * 16 + 255) / 256, 256, 0, stream>>>(pin, h0, dinv, rp, csr, pout, N);
        pin = pout;
    }
}

// Round 2
// 1534.650 us; speedup vs baseline: 1.3377x; 1.3377x over previous
//
#include <hip/hip_runtime.h>

// APPNP: h0 = relu(x@W1+b1)@W2+b2 ; 10x: h = 0.9*(D^-1/2 A_sl D^-1/2 h) + 0.1*h0
// Strategy: bf16-MFMA fused MLP; CSR-by-dst build once; gather-only propagation.
// norm factorization: agg[d] = dinv[d]*( sum_{e:dst=d} dinv[src]*h[src] ) + dinv[d]^2*h[d]
// R1: h stored fp16 during propagation (halves the dominant gather traffic);
//     accumulation stays fp32; h0 teleport term stays fp32.

typedef unsigned short u16;
typedef unsigned int   u32;
typedef __bf16    bfx8  __attribute__((ext_vector_type(8)));
typedef _Float16  h16x8 __attribute__((ext_vector_type(8)));
typedef float     f32x4 __attribute__((ext_vector_type(4)));

__device__ __forceinline__ u16 f2bf(float f) {
    u32 u = __float_as_uint(f);
    u += 0x7fffu + ((u >> 16) & 1u);   // RNE
    return (u16)(u >> 16);
}

// ---------------- graph build ----------------

__global__ void hist_kernel(const int* __restrict__ dst, int* __restrict__ indeg, int E) {
    int i = blockIdx.x * 256 + threadIdx.x;
    if (i < E) atomicAdd(&indeg[dst[i]], 1);
}

// block-level exclusive scan (1024/block), emits per-block totals
__global__ __launch_bounds__(1024) void scan1_kernel(const int* __restrict__ indeg,
                                                     int* __restrict__ rp,
                                                     int* __restrict__ bsum, int N) {
    __shared__ int tmp[1024];
    int tid = threadIdx.x;
    int i = blockIdx.x * 1024 + tid;
    int v = (i < N) ? indeg[i] : 0;
    tmp[tid] = v;
    __syncthreads();
    for (int off = 1; off < 1024; off <<= 1) {
        int t = 0;
        if (tid >= off) t = tmp[tid - off];
        __syncthreads();
        if (tid >= off) tmp[tid] += t;
        __syncthreads();
    }
    if (i < N) rp[i] = tmp[tid] - v;          // exclusive within block
    if (tid == 1023) bsum[blockIdx.x] = tmp[1023];
}

__global__ void scan2_kernel(const int* __restrict__ bsum, int* __restrict__ boff, int nb) {
    __shared__ int s[128];
    int tid = threadIdx.x;
    s[tid] = (tid < nb) ? bsum[tid] : 0;
    __syncthreads();
    if (tid == 0) {
        int run = 0;
        for (int j = 0; j < nb; ++j) { int t = s[j]; s[j] = run; run += t; }
    }
    __syncthreads();
    if (tid < nb) boff[tid] = s[tid];
}

__global__ void scan3_kernel(int* __restrict__ rp, const int* __restrict__ boff,
                             int* __restrict__ cursor, const int* __restrict__ indeg,
                             float* __restrict__ dinv, int N, int E) {
    int i = blockIdx.x * 256 + threadIdx.x;
    if (i < N) {
        int v = rp[i] + boff[i >> 10];
        rp[i] = v;
        cursor[i] = v;
        dinv[i] = rsqrtf(1.0f + (float)indeg[i]);   // +1 self-loop
    } else if (i == N) {
        rp[N] = E;
    }
}

__global__ void scatter_kernel(const int* __restrict__ src, const int* __restrict__ dst,
                               int* __restrict__ cursor, int* __restrict__ csr, int E) {
    int i = blockIdx.x * 256 + threadIdx.x;
    if (i < E) {
        int d = dst[i];
        int pos = atomicAdd(&cursor[d], 1);
        csr[pos] = src[i];
    }
}

// ---------------- weight pre-transpose to bf16 ----------------

__global__ void prepw1_kernel(const float* __restrict__ W1, u16* __restrict__ W1t) {
    int id = blockIdx.x * 256 + threadIdx.x;   // id = k*256 + n, k<512, n<256
    int k = id >> 8, n = id & 255;
    W1t[n * 512 + k] = f2bf(W1[id]);
}

__global__ void prepw2_kernel(const float* __restrict__ W2, u16* __restrict__ W2t) {
    int id = blockIdx.x * 256 + threadIdx.x;   // id = k*64 + n, k<256, n<64
    int k = id >> 6, n = id & 63;
    W2t[n * 256 + k] = f2bf(W2[id]);
}

// ---------------- fused MLP: out = relu(x@W1+b1)@W2+b2 -> h0 (fp32) and hA (fp16) ----------------
// block: 64 rows of x, 256 threads (4 waves). GEMM1: wave w covers hidden cols [64w,64w+64).
// mfma_f32_16x16x32_bf16: A[m=lane&15][k=(lane>>4)*8+j]; B[n=lane&15][k=same]; D col=lane&15,row=(lane>>4)*4+r

__global__ __launch_bounds__(256) void mlp_kernel(
        const float* __restrict__ x, const u16* __restrict__ W1t,
        const float* __restrict__ b1, const u16* __restrict__ W2t,
        const float* __restrict__ b2, float* __restrict__ h0,
        _Float16* __restrict__ hA, int N) {
    __shared__ char lds[65536];
    u16* xs  = (u16*)lds;              // phase1: [64][40] (pad 8 for banks), 5120 B
    u16* w1s = (u16*)(lds + 5120);     // phase1: [256][40], 20480 B
    u16* h1s = (u16*)lds;              // phase2: [64][256], 32768 B
    u16* w2s = (u16*)(lds + 32768);    // phase2: [64][256], 32768 B

    const int tid  = threadIdx.x;
    const int wave = tid >> 6;
    const int lane = tid & 63;
    const int lq   = lane >> 4;        // quad
    const int lr   = lane & 15;
    const int blockRow = blockIdx.x * 64;

    f32x4 acc[4][4];                   // [mt][nt]
#pragma unroll
    for (int a = 0; a < 4; ++a)
#pragma unroll
        for (int b = 0; b < 4; ++b) acc[a][b] = (f32x4){0.f, 0.f, 0.f, 0.f};

    // ---- GEMM1: K=512 in steps of 32 ----
    for (int kk = 0; kk < 512; kk += 32) {
        __syncthreads();
        // stage x tile 64x32 (fp32 -> bf16)
        {
            int r = tid >> 2, c = (tid & 3) << 3;       // 8 floats each
            int gr = blockRow + r;
            float v[8];
            if (gr < N) {
                const float* p = x + (size_t)gr * 512 + kk + c;
                float4 u0 = *(const float4*)p;
                float4 u1 = *(const float4*)(p + 4);
                v[0]=u0.x; v[1]=u0.y; v[2]=u0.z; v[3]=u0.w;
                v[4]=u1.x; v[5]=u1.y; v[6]=u1.z; v[7]=u1.w;
            } else {
#pragma unroll
                for (int j = 0; j < 8; ++j) v[j] = 0.f;
            }
            u32 pk[4];
#pragma unroll
            for (int j = 0; j < 4; ++j)
                pk[j] = (u32)f2bf(v[2*j]) | ((u32)f2bf(v[2*j+1]) << 16);
            uint4 st = make_uint4(pk[0], pk[1], pk[2], pk[3]);
            *(uint4*)&xs[r * 40 + c] = st;
        }
        // stage W1t tile 256x32 (already bf16, [n][k] layout)
        {
            const uint4* p = (const uint4*)(W1t + (size_t)tid * 512 + kk);
            uint4* q = (uint4*)&w1s[tid * 40];
            q[0] = p[0]; q[1] = p[1]; q[2] = p[2]; q[3] = p[3];
        }
        __syncthreads();
        bfx8 fa[4], fb[4];
#pragma unroll
        for (int mt = 0; mt < 4; ++mt)
            fa[mt] = *(bfx8*)&xs[(mt * 16 + lr) * 40 + lq * 8];
#pragma unroll
        for (int nt = 0; nt < 4; ++nt)
            fb[nt] = *(bfx8*)&w1s[(wave * 64 + nt * 16 + lr) * 40 + lq * 8];
#pragma unroll
        for (int mt = 0; mt < 4; ++mt)
#pragma unroll
            for (int nt = 0; nt < 4; ++nt)
                acc[mt][nt] = __builtin_amdgcn_mfma_f32_16x16x32_bf16(
                    fa[mt], fb[nt], acc[mt][nt], 0, 0, 0);
    }
    __syncthreads();   // done reading xs/w1s; reuse as h1s

    // ---- epilogue1: bias+relu -> h1s (bf16) ----
#pragma unroll
    for (int nt = 0; nt < 4; ++nt) {
        int col = wave * 64 + nt * 16 + lr;
        float bb = b1[col];
#pragma unroll
        for (int mt = 0; mt < 4; ++mt)
#pragma unroll
            for (int r = 0; r < 4; ++r) {
                int row = mt * 16 + lq * 4 + r;
                float v = acc[mt][nt][r] + bb;
                v = v > 0.f ? v : 0.f;
                h1s[row * 256 + col] = f2bf(v);
            }
    }
    // stage W2t [64][256] bf16
    {
        int nn = tid >> 2, seg = (tid & 3) * 64;
        const uint4* p = (const uint4*)(W2t + nn * 256 + seg);
        uint4* q = (uint4*)&w2s[nn * 256 + seg];
#pragma unroll
        for (int j = 0; j < 8; ++j) q[j] = p[j];
    }
    __syncthreads();

    // ---- GEMM2: wave w -> rows [16w,16w+16), cols 0..63, K=256 ----
    f32x4 acc2[4];
#pragma unroll
    for (int a = 0; a < 4; ++a) acc2[a] = (f32x4){0.f, 0.f, 0.f, 0.f};
    for (int kk = 0; kk < 256; kk += 32) {
        bfx8 a = *(bfx8*)&h1s[(wave * 16 + lr) * 256 + kk + lq * 8];
#pragma unroll
        for (int nt = 0; nt < 4; ++nt) {
            bfx8 b = *(bfx8*)&w2s[(nt * 16 + lr) * 256 + kk + lq * 8];
            acc2[nt] = __builtin_amdgcn_mfma_f32_16x16x32_bf16(a, b, acc2[nt], 0, 0, 0);
        }
    }
    // ---- epilogue2: bias, store to h0 (fp32) and hA (fp16) ----
#pragma unroll
    for (int nt = 0; nt < 4; ++nt) {
        int col = nt * 16 + lr;
        float bb = b2[col];
#pragma unroll
        for (int r = 0; r < 4; ++r) {
            int row = wave * 16 + lq * 4 + r;
            int gr = blockRow + row;
            if (gr < N) {
                float v = acc2[nt][r] + bb;
                size_t idx = (size_t)gr * 64 + col;
                h0[idx] = v;
                hA[idx] = (_Float16)v;
            }
        }
    }
}

// ---------------- propagation: gather-only, 8 threads/node, 16B (8 halves)/lane ----------------

template <typename OUTT>
__global__ __launch_bounds__(256) void prop_kernel(
        const _Float16* __restrict__ hin, const float* __restrict__ h0,
        const float* __restrict__ dinv, const int* __restrict__ rp,
        const int* __restrict__ csr, OUTT* __restrict__ hout, int N) {
    int t = blockIdx.x * 256 + threadIdx.x;
    int i = t >> 3;
    int l = t & 7;
    if (i >= N) return;
    int beg = rp[i], end = rp[i + 1];
    float a[8];
#pragma unroll
    for (int j = 0; j < 8; ++j) a[j] = 0.f;
    const _Float16* hbase = hin + l * 8;
    for (int e = beg; e < end; ++e) {
        int s = csr[e];
        float w = dinv[s];
        h16x8 g = *(const h16x8*)(hbase + (size_t)s * 64);
#pragma unroll
        for (int j = 0; j < 8; ++j) a[j] = fmaf(w, (float)g[j], a[j]);
    }
    float di = dinv[i];
    float c1 = 0.9f * di;
    float c2 = 0.9f * di * di;
    h16x8 hi = *(const h16x8*)(hbase + (size_t)i * 64);
    const float* h0p = h0 + (size_t)i * 64 + l * 8;
    float o[8];
#pragma unroll
    for (int j = 0; j < 8; ++j)
        o[j] = fmaf(c1, a[j], fmaf(c2, (float)hi[j], 0.1f * h0p[j]));
    if constexpr (sizeof(OUTT) == 2) {
        h16x8 ov;
#pragma unroll
        for (int j = 0; j < 8; ++j) ov[j] = (_Float16)o[j];
        *(h16x8*)(hout + (size_t)i * 64 + l * 8) = ov;
    } else {
        float4* q = (float4*)(hout + (size_t)i * 64 + l * 8);
        q[0] = make_float4(o[0], o[1], o[2], o[3]);
        q[1] = make_float4(o[4], o[5], o[6], o[7]);
    }
}

// ---------------- launch ----------------

extern "C" void kernel_launch(void* const* d_in, const int* in_sizes, int n_in,
                              void* d_out, int out_size, void* d_ws, size_t ws_size,
                              hipStream_t stream) {
    const float* x  = (const float*)d_in[0];
    const int*   ei = (const int*)d_in[1];
    const float* W1 = (const float*)d_in[2];
    const float* b1 = (const float*)d_in[3];
    const float* W2 = (const float*)d_in[4];
    const float* b2 = (const float*)d_in[5];
    const int N = in_sizes[0] / 512;
    const int E = in_sizes[1] / 2;
    const int* src = ei;
    const int* dst = ei + E;

    char* w = (char*)d_ws;
    size_t off = 0;
    auto alloc = [&](size_t bytes) -> char* {
        char* p = w + off;
        off = (off + bytes + 1023) & ~(size_t)1023;
        return p;
    };
    int*      indeg  = (int*)alloc((size_t)N * 4);
    int*      rp     = (int*)alloc(((size_t)N + 1) * 4);
    int*      cursor = (int*)alloc((size_t)N * 4);
    int*      bsum   = (int*)alloc(512);
    int*      boff   = (int*)alloc(512);
    float*    dinv   = (float*)alloc((size_t)N * 4);
    int*      csr    = (int*)alloc((size_t)E * 4);
    u16*      W1t    = (u16*)alloc(512 * 256 * 2);
    u16*      W2t    = (u16*)alloc(256 * 64 * 2);
    float*    h0     = (float*)alloc((size_t)N * 64 * 4);
    _Float16* hA     = (_Float16*)alloc((size_t)N * 64 * 2);
    _Float16* hB     = (_Float16*)alloc((size_t)N * 64 * 2);

    hipMemsetAsync(indeg, 0, (size_t)N * 4, stream);
    hist_kernel<<<(E + 255) / 256, 256, 0, stream>>>(dst, indeg, E);
    int nb = (N + 1023) / 1024;
    scan1_kernel<<<nb, 1024, 0, stream>>>(indeg, rp, bsum, N);
    scan2_kernel<<<1, 128, 0, stream>>>(bsum, boff, nb);
    scan3_kernel<<<(N + 256) / 256, 256, 0, stream>>>(rp, boff, cursor, indeg, dinv, N, E);
    scatter_kernel<<<(E + 255) / 256, 256, 0, stream>>>(src, dst, cursor, csr, E);
    prepw1_kernel<<<512, 256, 0, stream>>>(W1, W1t);
    prepw2_kernel<<<64, 256, 0, stream>>>(W2, W2t);
    mlp_kernel<<<(N + 63) / 64, 256, 0, stream>>>(x, W1t, b1, W2t, b2, h0, hA, N);

    const _Float16* pin = hA;
    int grid = (N * 8 + 255) / 256;
    for (int it = 0; it < 9; ++it) {
        _Float16* pout = (it & 1) ? hA : hB;
        prop_kernel<_Float16><<<grid, 256, 0, stream>>>(pin, h0, dinv, rp, csr, pout, N);
        pin = pout;
    }
    prop_kernel<float><<<grid, 256, 0, stream>>>(pin, h0, dinv, rp, csr, (float*)d_out, N);
}

// Round 3
// 1088.531 us; speedup vs baseline: 1.8860x; 1.4098x over previous
//
#include <hip/hip_runtime.h>

// APPNP: h0 = relu(x@W1+b1)@W2+b2 ; 10x: h = 0.9*(D^-1/2 A_sl D^-1/2 h) + 0.1*h0
// R2 build pipeline: bin edges by dst-bucket (64 nodes/bucket) with LDS-aggregated
//   reservation, then per-bucket CSR build entirely in LDS (coalesced final writes).
//   rp/dinv fall out of the bucket pass -> hist/scan kernels deleted.
// R2 prop: store hs = dinv*h (fp16); gather loop is a pure sum (no per-edge dinv).
//   h_new = 0.9*dinv[d]*(sum_in hs + hs[d]) + 0.1*h0[d]

typedef unsigned short u16;
typedef unsigned int   u32;
typedef __bf16    bfx8  __attribute__((ext_vector_type(8)));
typedef _Float16  h16x8 __attribute__((ext_vector_type(8)));
typedef float     f32x4 __attribute__((ext_vector_type(4)));

#define CAP 4096      // per-bucket edge capacity (mean 2048, sigma 45 -> 45 sigma margin)
#define EPB 16384     // edges per binscat block
#define NBMAX 1792    // bucket count upper bound for LDS arrays (N<=114k)

__device__ __forceinline__ u16 f2bf(float f) {
    u32 u = __float_as_uint(f);
    u += 0x7fffu + ((u >> 16) & 1u);   // RNE
    return (u16)(u >> 16);
}

// ---------------- build pass 1: bin edges by dst bucket ----------------

__global__ __launch_bounds__(256) void binscat_kernel(
        const int* __restrict__ src, const int* __restrict__ dst,
        int* __restrict__ gcur, u32* __restrict__ binned, int E, int NB) {
    __shared__ int cnt[NBMAX];
    int tid = threadIdx.x;
#pragma unroll
    for (int j = 0; j < NBMAX / 256; ++j) cnt[tid + j * 256] = 0;
    __syncthreads();
    int e0 = blockIdx.x * EPB;
    // count
    for (int r = 0; r < EPB / 256; ++r) {
        int i = e0 + r * 256 + tid;
        if (i < E) atomicAdd(&cnt[dst[i] >> 6], 1);
    }
    __syncthreads();
    // reserve: one global atomic per (block,bucket); cnt[b] becomes global cursor
    for (int j = 0; j < NBMAX / 256; ++j) {
        int b = tid + j * 256;
        if (b < NB) {
            int c = cnt[b];
            cnt[b] = (c > 0) ? atomicAdd(&gcur[b], c) : 0;
        }
    }
    __syncthreads();
    // place: pack (local_dst<<17)|src into 4B
    for (int r = 0; r < EPB / 256; ++r) {
        int i = e0 + r * 256 + tid;
        if (i < E) {
            int d = dst[i];
            int s = src[i];
            int bb = d >> 6;
            int p = atomicAdd(&cnt[bb], 1);
            if (p < CAP) binned[(size_t)bb * CAP + p] = ((u32)(d & 63) << 17) | (u32)s;
        }
    }
}

// ---------------- build pass 2: exclusive scan of bucket counts ----------------

__global__ __launch_bounds__(256) void bucket_scan_kernel(
        const int* __restrict__ gcur, int* __restrict__ bbase,
        int* __restrict__ rp, int N, int NB) {
    __shared__ int tsum[256];
    int tid = threadIdx.x;
    int loc[7];
    int run = 0;
#pragma unroll
    for (int j = 0; j < 7; ++j) {
        int b = tid * 7 + j;
        int v = 0;
        if (b < NB) { v = gcur[b]; if (v > CAP) v = CAP; }
        loc[j] = run;
        run += v;
    }
    tsum[tid] = run;
    __syncthreads();
    for (int off = 1; off < 256; off <<= 1) {
        int t = (tid >= off) ? tsum[tid - off] : 0;
        __syncthreads();
        tsum[tid] += t;
        __syncthreads();
    }
    int texcl = tsum[tid] - run;
#pragma unroll
    for (int j = 0; j < 7; ++j) {
        int b = tid * 7 + j;
        if (b < NB) bbase[b] = texcl + loc[j];
    }
    if (tid == 255) rp[N] = tsum[255];   // == E
}

// ---------------- build pass 3: per-bucket CSR in LDS (+rp,+dinv) ----------------

__global__ __launch_bounds__(256) void buildcsr_kernel(
        const u32* __restrict__ binned, const int* __restrict__ gcur,
        const int* __restrict__ bbase, int* __restrict__ rp,
        float* __restrict__ dinv, int* __restrict__ csr, int N) {
    __shared__ u32 eb[CAP];        // staged packed edges (16 KB)
    __shared__ int lcsr[CAP];      // bucket-local csr (16 KB)
    __shared__ int ncnt[64];
    __shared__ int lcur[64];
    int b = blockIdx.x;
    int tid = threadIdx.x;
    int cnt = gcur[b]; if (cnt > CAP) cnt = CAP;
    int base = bbase[b];
    if (tid < 64) ncnt[tid] = 0;
    __syncthreads();
    for (int idx = tid; idx < cnt; idx += 256) {
        u32 v = binned[(size_t)b * CAP + idx];
        eb[idx] = v;
        atomicAdd(&ncnt[v >> 17], 1);
    }
    __syncthreads();
    if (tid < 64) {   // wave 0: 64-wide exclusive scan + rp/dinv emit
        int c = ncnt[tid];
        int s = c;
#pragma unroll
        for (int off = 1; off < 64; off <<= 1) {
            int t = __shfl_up(s, off);
            if (tid >= off) s += t;
        }
        int excl = s - c;
        lcur[tid] = excl;
        int node = b * 64 + tid;
        if (node < N) {
            rp[node] = base + excl;
            dinv[node] = rsqrtf(1.0f + (float)c);   // +1 self-loop
        }
    }
    __syncthreads();
    for (int idx = tid; idx < cnt; idx += 256) {
        u32 v = eb[idx];
        int p = atomicAdd(&lcur[v >> 17], 1);
        lcsr[p] = (int)(v & 0x1FFFFu);
    }
    __syncthreads();
    for (int idx = tid; idx < cnt; idx += 256)
        csr[base + idx] = lcsr[idx];   // fully coalesced
}

// ---------------- weight pre-transpose to bf16 ----------------

__global__ void prepw1_kernel(const float* __restrict__ W1, u16* __restrict__ W1t) {
    int id = blockIdx.x * 256 + threadIdx.x;   // id = k*256 + n, k<512, n<256
    int k = id >> 8, n = id & 255;
    W1t[n * 512 + k] = f2bf(W1[id]);
}

__global__ void prepw2_kernel(const float* __restrict__ W2, u16* __restrict__ W2t) {
    int id = blockIdx.x * 256 + threadIdx.x;   // id = k*64 + n, k<256, n<64
    int k = id >> 6, n = id & 63;
    W2t[n * 256 + k] = f2bf(W2[id]);
}

// ---------------- fused MLP -> h0 (fp32) and hs = dinv*h0 (fp16) ----------------
// block: 64 rows of x, 256 threads (4 waves). GEMM1: wave w covers hidden cols [64w,64w+64).
// mfma_f32_16x16x32_bf16: A[m=lane&15][k=(lane>>4)*8+j]; B[n=lane&15][k=same]; D col=lane&15,row=(lane>>4)*4+r

__global__ __launch_bounds__(256) void mlp_kernel(
        const float* __restrict__ x, const u16* __restrict__ W1t,
        const float* __restrict__ b1, const u16* __restrict__ W2t,
        const float* __restrict__ b2, const float* __restrict__ dinv,
        float* __restrict__ h0, _Float16* __restrict__ hA, int N) {
    __shared__ char lds[65536];
    u16* xs  = (u16*)lds;              // phase1: [64][40] (pad 8 for banks), 5120 B
    u16* w1s = (u16*)(lds + 5120);     // phase1: [256][40], 20480 B
    u16* h1s = (u16*)lds;              // phase2: [64][256], 32768 B
    u16* w2s = (u16*)(lds + 32768);    // phase2: [64][256], 32768 B

    const int tid  = threadIdx.x;
    const int wave = tid >> 6;
    const int lane = tid & 63;
    const int lq   = lane >> 4;        // quad
    const int lr   = lane & 15;
    const int blockRow = blockIdx.x * 64;

    f32x4 acc[4][4];                   // [mt][nt]
#pragma unroll
    for (int a = 0; a < 4; ++a)
#pragma unroll
        for (int b = 0; b < 4; ++b) acc[a][b] = (f32x4){0.f, 0.f, 0.f, 0.f};

    // ---- GEMM1: K=512 in steps of 32 ----
    for (int kk = 0; kk < 512; kk += 32) {
        __syncthreads();
        // stage x tile 64x32 (fp32 -> bf16)
        {
            int r = tid >> 2, c = (tid & 3) << 3;       // 8 floats each
            int gr = blockRow + r;
            float v[8];
            if (gr < N) {
                const float* p = x + (size_t)gr * 512 + kk + c;
                float4 u0 = *(const float4*)p;
                float4 u1 = *(const float4*)(p + 4);
                v[0]=u0.x; v[1]=u0.y; v[2]=u0.z; v[3]=u0.w;
                v[4]=u1.x; v[5]=u1.y; v[6]=u1.z; v[7]=u1.w;
            } else {
#pragma unroll
                for (int j = 0; j < 8; ++j) v[j] = 0.f;
            }
            u32 pk[4];
#pragma unroll
            for (int j = 0; j < 4; ++j)
                pk[j] = (u32)f2bf(v[2*j]) | ((u32)f2bf(v[2*j+1]) << 16);
            uint4 st = make_uint4(pk[0], pk[1], pk[2], pk[3]);
            *(uint4*)&xs[r * 40 + c] = st;
        }
        // stage W1t tile 256x32 (already bf16, [n][k] layout)
        {
            const uint4* p = (const uint4*)(W1t + (size_t)tid * 512 + kk);
            uint4* q = (uint4*)&w1s[tid * 40];
            q[0] = p[0]; q[1] = p[1]; q[2] = p[2]; q[3] = p[3];
        }
        __syncthreads();
        bfx8 fa[4], fb[4];
#pragma unroll
        for (int mt = 0; mt < 4; ++mt)
            fa[mt] = *(bfx8*)&xs[(mt * 16 + lr) * 40 + lq * 8];
#pragma unroll
        for (int nt = 0; nt < 4; ++nt)
            fb[nt] = *(bfx8*)&w1s[(wave * 64 + nt * 16 + lr) * 40 + lq * 8];
#pragma unroll
        for (int mt = 0; mt < 4; ++mt)
#pragma unroll
            for (int nt = 0; nt < 4; ++nt)
                acc[mt][nt] = __builtin_amdgcn_mfma_f32_16x16x32_bf16(
                    fa[mt], fb[nt], acc[mt][nt], 0, 0, 0);
    }
    __syncthreads();   // done reading xs/w1s; reuse as h1s

    // ---- epilogue1: bias+relu -> h1s (bf16) ----
#pragma unroll
    for (int nt = 0; nt < 4; ++nt) {
        int col = wave * 64 + nt * 16 + lr;
        float bb = b1[col];
#pragma unroll
        for (int mt = 0; mt < 4; ++mt)
#pragma unroll
            for (int r = 0; r < 4; ++r) {
                int row = mt * 16 + lq * 4 + r;
                float v = acc[mt][nt][r] + bb;
                v = v > 0.f ? v : 0.f;
                h1s[row * 256 + col] = f2bf(v);
            }
    }
    // stage W2t [64][256] bf16
    {
        int nn = tid >> 2, seg = (tid & 3) * 64;
        const uint4* p = (const uint4*)(W2t + nn * 256 + seg);
        uint4* q = (uint4*)&w2s[nn * 256 + seg];
#pragma unroll
        for (int j = 0; j < 8; ++j) q[j] = p[j];
    }
    __syncthreads();

    // ---- GEMM2: wave w -> rows [16w,16w+16), cols 0..63, K=256 ----
    f32x4 acc2[4];
#pragma unroll
    for (int a = 0; a < 4; ++a) acc2[a] = (f32x4){0.f, 0.f, 0.f, 0.f};
    for (int kk = 0; kk < 256; kk += 32) {
        bfx8 a = *(bfx8*)&h1s[(wave * 16 + lr) * 256 + kk + lq * 8];
#pragma unroll
        for (int nt = 0; nt < 4; ++nt) {
            bfx8 b = *(bfx8*)&w2s[(nt * 16 + lr) * 256 + kk + lq * 8];
            acc2[nt] = __builtin_amdgcn_mfma_f32_16x16x32_bf16(a, b, acc2[nt], 0, 0, 0);
        }
    }
    // ---- epilogue2: bias, store h0 (fp32) and hs=dinv*h0 (fp16) ----
#pragma unroll
    for (int nt = 0; nt < 4; ++nt) {
        int col = nt * 16 + lr;
        float bb = b2[col];
#pragma unroll
        for (int r = 0; r < 4; ++r) {
            int row = wave * 16 + lq * 4 + r;
            int gr = blockRow + row;
            if (gr < N) {
                float v = acc2[nt][r] + bb;
                size_t idx = (size_t)gr * 64 + col;
                h0[idx] = v;
                hA[idx] = (_Float16)(v * dinv[gr]);
            }
        }
    }
}

// ---------------- propagation: 8 threads/node, 16B/lane, pure-sum gather ----------------

template <typename OUTT>
__global__ __launch_bounds__(256) void prop_kernel(
        const _Float16* __restrict__ hs, const float* __restrict__ h0,
        const float* __restrict__ dinv, const int* __restrict__ rp,
        const int* __restrict__ csr, OUTT* __restrict__ hout, int N) {
    int t = blockIdx.x * 256 + threadIdx.x;
    int i = t >> 3;
    int l = t & 7;
    if (i >= N) return;
    int beg = rp[i], end = rp[i + 1];
    const _Float16* hb = hs + l * 8;
    h16x8 self = *(const h16x8*)(hb + (size_t)i * 64);
    float a[8];
#pragma unroll
    for (int j = 0; j < 8; ++j) a[j] = (float)self[j];   // self-loop folded into init
    int e = beg;
    for (; e + 1 < end; e += 2) {                        // 2x unroll for MLP
        int s0 = csr[e], s1 = csr[e + 1];
        h16x8 g0 = *(const h16x8*)(hb + (size_t)s0 * 64);
        h16x8 g1 = *(const h16x8*)(hb + (size_t)s1 * 64);
#pragma unroll
        for (int j = 0; j < 8; ++j) a[j] += (float)g0[j];
#pragma unroll
        for (int j = 0; j < 8; ++j) a[j] += (float)g1[j];
    }
    if (e < end) {
        int s0 = csr[e];
        h16x8 g0 = *(const h16x8*)(hb + (size_t)s0 * 64);
#pragma unroll
        for (int j = 0; j < 8; ++j) a[j] += (float)g0[j];
    }
    float dv = dinv[i];
    float c1 = 0.9f * dv;
    const float* h0p = h0 + (size_t)i * 64 + l * 8;
    float o[8];
#pragma unroll
    for (int j = 0; j < 8; ++j) o[j] = fmaf(c1, a[j], 0.1f * h0p[j]);
    if constexpr (sizeof(OUTT) == 2) {
        h16x8 ov;
#pragma unroll
        for (int j = 0; j < 8; ++j) ov[j] = (_Float16)(dv * o[j]);   // store hs_new
        *(h16x8*)(hout + (size_t)i * 64 + l * 8) = ov;
    } else {
        float4* q = (float4*)(hout + (size_t)i * 64 + l * 8);
        q[0] = make_float4(o[0], o[1], o[2], o[3]);
        q[1] = make_float4(o[4], o[5], o[6], o[7]);
    }
}

// ---------------- launch ----------------

extern "C" void kernel_launch(void* const* d_in, const int* in_sizes, int n_in,
                              void* d_out, int out_size, void* d_ws, size_t ws_size,
                              hipStream_t stream) {
    const float* x  = (const float*)d_in[0];
    const int*   ei = (const int*)d_in[1];
    const float* W1 = (const float*)d_in[2];
    const float* b1 = (const float*)d_in[3];
    const float* W2 = (const float*)d_in[4];
    const float* b2 = (const float*)d_in[5];
    const int N = in_sizes[0] / 512;
    const int E = in_sizes[1] / 2;
    const int NB = (N + 63) / 64;
    const int* src = ei;
    const int* dst = ei + E;

    char* w = (char*)d_ws;
    size_t off = 0;
    auto alloc = [&](size_t bytes) -> char* {
        char* p = w + off;
        off = (off + bytes + 1023) & ~(size_t)1023;
        return p;
    };
    int*      gcur  = (int*)alloc((size_t)NB * 4);
    int*      bbase = (int*)alloc((size_t)NB * 4);
    int*      rp    = (int*)alloc(((size_t)N + 1) * 4);
    float*    dinv  = (float*)alloc((size_t)N * 4);
    int*      csr   = (int*)alloc((size_t)E * 4);
    u32*      binned= (u32*)alloc((size_t)NB * CAP * 4);
    u16*      W1t   = (u16*)alloc(512 * 256 * 2);
    u16*      W2t   = (u16*)alloc(256 * 64 * 2);
    float*    h0    = (float*)alloc((size_t)N * 64 * 4);
    _Float16* hA    = (_Float16*)alloc((size_t)N * 64 * 2);
    _Float16* hB    = (_Float16*)alloc((size_t)N * 64 * 2);
    // ws use ~91 MB

    hipMemsetAsync(gcur, 0, (size_t)NB * 4, stream);
    binscat_kernel<<<(E + EPB - 1) / EPB, 256, 0, stream>>>(src, dst, gcur, binned, E, NB);
    bucket_scan_kernel<<<1, 256, 0, stream>>>(gcur, bbase, rp, N, NB);
    buildcsr_kernel<<<NB, 256, 0, stream>>>(binned, gcur, bbase, rp, dinv, csr, N);
    prepw1_kernel<<<512, 256, 0, stream>>>(W1, W1t);
    prepw2_kernel<<<64, 256, 0, stream>>>(W2, W2t);
    mlp_kernel<<<(N + 63) / 64, 256, 0, stream>>>(x, W1t, b1, W2t, b2, dinv, h0, hA, N);

    const _Float16* pin = hA;
    int grid = (N * 8 + 255) / 256;
    for (int it = 0; it < 9; ++it) {
        _Float16* pout = (it & 1) ? hA : hB;
        prop_kernel<_Float16><<<grid, 256, 0, stream>>>(pin, h0, dinv, rp, csr, pout, N);
        pin = pout;
    }
    prop_kernel<float><<<grid, 256, 0, stream>>>(pin, h0, dinv, rp, csr, (float*)d_out, N);
}